// Round 22
// baseline (103.401 us; speedup 1.0000x reference)
//
#include <hip/hip_runtime.h>
#include <hip/hip_bf16.h>

#define D 512
#define BM 128
#define NKT 8                 // 8 K-tiles of 64 (full K resident)
#define NT 64                 // 8192 / 128 column-panels
#define NBLK (NT*(NT+1)/2)    // 2080 triangular tiles (2080 = 8*260)
#define XCHUNK (NBLK/8)       // 260 tiles per XCD chunk
#define N2ROWS 8192
#define PANEL (BM*D)          // 65536 B per full panel
#define GRID 256              // persistent: 1 block/CU, ~8 tiles each

typedef __attribute__((ext_vector_type(4))) int i32x4;

// async global -> LDS, 16B per lane; LDS dest is wave-uniform base + lane*16
__device__ inline void gload16b(const char* g, char* l) {
    __builtin_amdgcn_global_load_lds(
        (const __attribute__((address_space(1))) unsigned int*)g,
        (__attribute__((address_space(3))) unsigned int*)l,
        16, 0, 0);
}

// Kernel A: 4 rows per block (512 thr). Row L2-norms, per-row-max int8 quant
// Qn[2N][D], rscale[2N], pos[i]=exp(2*cos) fp32; zeroes total+ticket.
__global__ __launch_bounds__(512) void prep_kernel(const float* __restrict__ y,
                                                   const float* __restrict__ yh,
                                                   char* __restrict__ Qn,
                                                   float* __restrict__ rscale,
                                                   float* __restrict__ pos,
                                                   float* __restrict__ total,
                                                   int* __restrict__ ticket, int N) {
    const int t = threadIdx.x;
    const int g = t >> 7;           // row-group 0..3
    const int tl = t & 127;         // lane within group
    const int i = blockIdx.x * 4 + g;
    if (blockIdx.x == 0) {
        if (t == 0) total[0] = 0.f;
        if (t == 1) ticket[0] = 0;
    }
    const float4 a = ((const float4*)(y + (size_t)i * D))[tl];
    const float4 b = ((const float4*)(yh + (size_t)i * D))[tl];
    float sy = a.x*a.x + a.y*a.y + a.z*a.z + a.w*a.w;
    float sh = b.x*b.x + b.y*b.y + b.z*b.z + b.w*b.w;
    float sd = a.x*b.x + a.y*b.y + a.z*b.z + a.w*b.w;
    float ma = fmaxf(fmaxf(fabsf(a.x), fabsf(a.y)), fmaxf(fabsf(a.z), fabsf(a.w)));
    float mb = fmaxf(fmaxf(fabsf(b.x), fabsf(b.y)), fmaxf(fabsf(b.z), fabsf(b.w)));
    #pragma unroll
    for (int o = 32; o > 0; o >>= 1) {
        sy += __shfl_xor(sy, o);
        sh += __shfl_xor(sh, o);
        sd += __shfl_xor(sd, o);
        ma = fmaxf(ma, __shfl_xor(ma, o));
        mb = fmaxf(mb, __shfl_xor(mb, o));
    }
    __shared__ float red[4][5][2];
    const int wv = tl >> 6;
    if ((tl & 63) == 0) {
        red[g][0][wv] = sy; red[g][1][wv] = sh; red[g][2][wv] = sd;
        red[g][3][wv] = ma; red[g][4][wv] = mb;
    }
    __syncthreads();
    sy = red[g][0][0] + red[g][0][1];
    sh = red[g][1][0] + red[g][1][1];
    sd = red[g][2][0] + red[g][2][1];
    ma = fmaxf(fmaxf(red[g][3][0], red[g][3][1]), 1e-20f);
    mb = fmaxf(fmaxf(red[g][4][0], red[g][4][1]), 1e-20f);
    const float ny = sqrtf(sy), nh = sqrtf(sh);
    const float ry = 1.f / fmaxf(ny, 1e-12f), rh = 1.f / fmaxf(nh, 1e-12f);
    const float qa = 127.f / ma, qb = 127.f / mb;
    const int ax = (int)rintf(a.x * qa), ay = (int)rintf(a.y * qa),
              az = (int)rintf(a.z * qa), aw = (int)rintf(a.w * qa);
    const int bx_ = (int)rintf(b.x * qb), by_ = (int)rintf(b.y * qb),
              bz = (int)rintf(b.z * qb), bw = (int)rintf(b.w * qb);
    const unsigned int pa = (ax & 0xff) | ((ay & 0xff) << 8) | ((az & 0xff) << 16) | ((aw & 0xff) << 24);
    const unsigned int pb = (bx_ & 0xff) | ((by_ & 0xff) << 8) | ((bz & 0xff) << 16) | ((bw & 0xff) << 24);
    ((unsigned int*)(Qn + (size_t)i * D))[tl] = pa;
    ((unsigned int*)(Qn + (size_t)(i + N) * D))[tl] = pb;
    if (tl == 0) {
        rscale[i]     = ma * ry / 127.f;
        rscale[i + N] = mb * rh / 127.f;
        const float cs = sd / (fmaxf(ny, 1e-8f) * fmaxf(nh, 1e-8f));
        pos[i] = __expf(2.f * cs);
    }
}

// Kernel B: PERSISTENT full-panel-resident design. Each block loops over
// ~8 triangular 128x128 tiles. Per tile: both FULL K=512 panels live in LDS
// (64+64 KB), so the 8-K-tile MFMA loop has ZERO barriers (compiler pipelines
// ds_read/MFMA across K freely). Next tile's 128 KB DMA is issued right after
// the post-K barrier and drains under the epilogue (exp/reduce/stores).
// 2 syncs per tile (vs 16 in the K-staged designs).
// Swizzle: phys 16B-chunk = logical ^ (row&7); staging source pre-swizzled
// with the same involution (j-invariant: rows advance by 8 per issue).
__global__ __launch_bounds__(256) void simgemm_kernel(const char* __restrict__ Qn,
                                                      const float* __restrict__ rscale,
                                                      float* __restrict__ slab) {
    __shared__ char As[PANEL];         // 64 KB
    __shared__ char Bs[PANEL];         // 64 KB
    __shared__ float redR[128][2];     // 1 KB
    __shared__ float redC[128][2];     // 1 KB   (130 KB -> 1 block/CU)
    const int tid = threadIdx.x;
    const int lane = tid & 63;
    const int w = tid >> 6;            // 0..3
    const int wm = (w >> 1) * 64;
    const int wn = (w & 1) * 64;
    const int fr = lane & 15;
    const int fq = lane >> 4;
    const int sw = fr & 7;             // swizzle key (row&7 == fr&7 for all frag rows)

    // hoisted ds_read row terms
    int rowAterm[4], rowBterm[4];
    #pragma unroll
    for (int m = 0; m < 4; ++m) rowAterm[m] = (wm + m * 16 + fr) * D;
    #pragma unroll
    for (int n = 0; n < 4; ++n) rowBterm[n] = (wn + n * 16 + fr) * D;

    // staging geometry: issue j (0..15) per panel; wave w writes 1KB at
    // (4j+w)*1024 covering rows 8j + srow0, srow0 = 2w + (lane>>5) in 0..7.
    // phys chunk p = lane&31 holds logical chunk p ^ (row&7) = p ^ srow0.
    const int srow0 = 2 * w + (lane >> 5);
    const int cl = (lane & 31) ^ srow0;
    const int goff0 = srow0 * D + cl * 16;     // + tile row base * D
    const int loff0 = w * 1024;                // + j*4096

    auto STAGE = [&](int bxT, int byT) {
        const char* gA = Qn + (size_t)byT * BM * D + goff0;
        const char* gB = Qn + (size_t)bxT * BM * D + goff0;
        #pragma unroll
        for (int j = 0; j < 16; ++j)
            gload16b(gA + j * 4096, As + loff0 + j * 4096);
        #pragma unroll
        for (int j = 0; j < 16; ++j)
            gload16b(gB + j * 4096, Bs + loff0 + j * 4096);
    };

    auto decode = [&](int t0, int& bxT, int& byT) {
        const int tt = (t0 & 7) * XCHUNK + (t0 >> 3);
        int b = (int)((sqrtf(8.f * (float)tt + 1.f) - 1.f) * 0.5f);
        while ((b + 1) * (b + 2) / 2 <= tt) ++b;
        while (b * (b + 1) / 2 > tt) --b;
        bxT = b;
        byT = tt - b * (b + 1) / 2;
    };

    int t0 = blockIdx.x;
    int bx, by;
    decode(t0, bx, by);
    STAGE(bx, by);

    for (;;) {
        __syncthreads();               // panels drained (prologue or prev combine-sync)
        i32x4 acc[4][4];
        #pragma unroll
        for (int m = 0; m < 4; ++m)
            #pragma unroll
            for (int n = 0; n < 4; ++n) acc[m][n] = (i32x4){0, 0, 0, 0};

        // ---- barrier-free K-loop over the resident panels
        #pragma unroll
        for (int kt = 0; kt < NKT; ++kt) {
            const int koff = (((kt << 2) | fq) ^ sw) << 4;
            i32x4 fa[4], bb[4];
            #pragma unroll
            for (int m = 0; m < 4; ++m) fa[m] = *(const i32x4*)(As + rowAterm[m] + koff);
            #pragma unroll
            for (int n = 0; n < 4; ++n) bb[n] = *(const i32x4*)(Bs + rowBterm[n] + koff);
            #pragma unroll
            for (int m = 0; m < 4; ++m)
                #pragma unroll
                for (int n = 0; n < 4; ++n)
                    acc[m][n] = __builtin_amdgcn_mfma_i32_16x16x64_i8(fa[m], bb[n], acc[m][n], 0, 0, 0);
        }
        __syncthreads();               // all panel reads complete block-wide

        // issue next tile's DMA now — drains under the epilogue below
        const int bxs = bx, bys = by;
        const int t0n = t0 + GRID;
        const bool more = (t0n < NBLK);
        if (more) {
            decode(t0n, bx, by);
            STAGE(bx, by);
            t0 = t0n;
        }

        // ---- epilogue for tile (bxs,bys): dequant, exp, partial sums
        const int rowA0 = bys * BM, rowB0 = bxs * BM;
        const bool diagblk = (bxs == bys);
        float rsb4[4];
        #pragma unroll
        for (int n = 0; n < 4; ++n) rsb4[n] = rscale[rowB0 + wn + n * 16 + fr];
        float colv[4] = {0.f, 0.f, 0.f, 0.f};
        #pragma unroll
        for (int m = 0; m < 4; ++m)
            #pragma unroll
            for (int r = 0; r < 4; ++r) {
                const int grow = wm + m * 16 + fq * 4 + r;
                const float rsa = rscale[rowA0 + grow];
                float rv = 0.f;
                #pragma unroll
                for (int n = 0; n < 4; ++n) {
                    const float f = (float)acc[m][n][r] * rsa * rsb4[n];
                    float e = __expf(2.f * f);
                    const bool diag = diagblk && grow == (wn + n * 16 + fr);
                    e = diag ? 0.f : e;
                    rv += e;
                    colv[n] += e;
                }
                rv += __shfl_xor(rv, 1);
                rv += __shfl_xor(rv, 2);
                rv += __shfl_xor(rv, 4);
                rv += __shfl_xor(rv, 8);
                if (fr == 0) redR[grow][w & 1] = rv;
            }
        if (!diagblk) {
            #pragma unroll
            for (int n = 0; n < 4; ++n) {
                float v = colv[n];
                v += __shfl_xor(v, 16);
                v += __shfl_xor(v, 32);
                if (fq == 0) redC[wn + n * 16 + fr][w >> 1] = v;
            }
        }
        __syncthreads();               // combine rendezvous; also drains next-tile DMA
        if (tid < 128) {
            slab[(size_t)bxs * N2ROWS + rowA0 + tid] = redR[tid][0] + redR[tid][1];
        } else if (!diagblk) {
            const int c = tid - 128;
            slab[(size_t)bys * N2ROWS + rowB0 + c] = redC[c][0] + redC[c][1];
        }
        if (!more) break;
    }
}

// Kernel C (fused): per-row neg over 64 panels, s = pos/neg, block reduce,
// atomic total; the LAST block (device-scope ticket) computes the final loss.
__global__ __launch_bounds__(256) void reduce_kernel(const float* __restrict__ slab,
                                                     const float* __restrict__ pos,
                                                     float* __restrict__ total,
                                                     int* __restrict__ ticket,
                                                     float* __restrict__ out, int N) {
    const int i = blockIdx.x * 256 + threadIdx.x;   // 0..8191
    float neg = 0.f;
    #pragma unroll
    for (int q = 0; q < NT; ++q) neg += slab[(size_t)q * N2ROWS + i];
    const float p = pos[i < N ? i : i - N];
    float s = p / neg;
    #pragma unroll
    for (int o = 32; o > 0; o >>= 1) s += __shfl_xor(s, o);
    __shared__ float red[4];
    if ((threadIdx.x & 63) == 0) red[threadIdx.x >> 6] = s;
    __syncthreads();
    if (threadIdx.x == 0) {
        atomicAdd(total, red[0] + red[1] + red[2] + red[3]);
        __threadfence();
        const int my = atomicAdd(ticket, 1);
        if (my == gridDim.x - 1) {
            const float tot = atomicAdd(total, 0.f);   // device-scope read after all adds
            out[0] = logf(2.f * (float)N) - logf(tot);
        }
    }
}

extern "C" void kernel_launch(void* const* d_in, const int* in_sizes, int n_in,
                              void* d_out, int out_size, void* d_ws, size_t ws_size,
                              hipStream_t stream) {
    const float* y  = (const float*)d_in[0];
    const float* yh = (const float*)d_in[1];
    const int N  = in_sizes[0] / D;   // 4096
    const int N2 = 2 * N;             // 8192

    char* Qn = (char*)d_ws;                                      // [2N][D] i8, 4 MB
    const size_t qn_bytes = (size_t)N2 * D;
    float* slab   = (float*)((char*)d_ws + qn_bytes);            // [64][8192] = 2 MB
    float* pos    = slab + (size_t)NT * N2ROWS;                  // [N]
    float* total  = pos + N;                                     // [1]
    float* rscale = total + 1;                                   // [2N]
    int*   ticket = (int*)(rscale + N2);                         // [1]
    float* out = (float*)d_out;

    prep_kernel<<<N / 4, 512, 0, stream>>>(y, yh, Qn, rscale, pos, total, ticket, N);
    simgemm_kernel<<<GRID, 256, 0, stream>>>(Qn, rscale, slab);
    reduce_kernel<<<N2 / 256, 256, 0, stream>>>(slab, pos, total, ticket, out, N);
}

// Round 23
// 66.663 us; speedup vs baseline: 1.5511x; 1.5511x over previous
//
#include <hip/hip_runtime.h>
#include <hip/hip_bf16.h>

#define D 512
#define BM 256
#define BKB 64                // K-tile bytes per row (64 i8 elements)
#define NKT 8                 // 512 / 64
#define NT 32                 // 8192 / 256
#define NBLK (NT*(NT+1)/2)    // 528 triangular blocks (528 = 8*66)
#define XCHUNK (NBLK/8)       // 66 blocks per XCD chunk
#define N2ROWS 8192
#define ABYTES (BM*BKB)       // 16384 per buffer

typedef __attribute__((ext_vector_type(4))) int i32x4;

// async global -> LDS, 16B per lane; LDS dest is wave-uniform base + lane*16
__device__ inline void gload16b(const char* g, char* l) {
    __builtin_amdgcn_global_load_lds(
        (const __attribute__((address_space(1))) unsigned int*)g,
        (__attribute__((address_space(3))) unsigned int*)l,
        16, 0, 0);
}

// Kernel A (R18's lean 128-thread version): row L2-norms, per-row-max int8
// quant Qn[2N][D], rscale[2N], pos[i]=exp(2*cos) fp32; zeroes total+ticket.
__global__ __launch_bounds__(128) void prep_kernel(const float* __restrict__ y,
                                                   const float* __restrict__ yh,
                                                   char* __restrict__ Qn,
                                                   float* __restrict__ rscale,
                                                   float* __restrict__ pos,
                                                   float* __restrict__ total,
                                                   int* __restrict__ ticket, int N) {
    const int i = blockIdx.x;
    const int t = threadIdx.x;
    if (i == 0) {
        if (t == 0) total[0] = 0.f;
        if (t == 1) ticket[0] = 0;
    }
    const float4 a = ((const float4*)(y + (size_t)i * D))[t];
    const float4 b = ((const float4*)(yh + (size_t)i * D))[t];
    float sy = a.x*a.x + a.y*a.y + a.z*a.z + a.w*a.w;
    float sh = b.x*b.x + b.y*b.y + b.z*b.z + b.w*b.w;
    float sd = a.x*b.x + a.y*b.y + a.z*b.z + a.w*b.w;
    float ma = fmaxf(fmaxf(fabsf(a.x), fabsf(a.y)), fmaxf(fabsf(a.z), fabsf(a.w)));
    float mb = fmaxf(fmaxf(fabsf(b.x), fabsf(b.y)), fmaxf(fabsf(b.z), fabsf(b.w)));
    #pragma unroll
    for (int o = 32; o > 0; o >>= 1) {
        sy += __shfl_xor(sy, o);
        sh += __shfl_xor(sh, o);
        sd += __shfl_xor(sd, o);
        ma = fmaxf(ma, __shfl_xor(ma, o));
        mb = fmaxf(mb, __shfl_xor(mb, o));
    }
    __shared__ float red[5][2];
    const int wv = t >> 6;
    if ((t & 63) == 0) { red[0][wv] = sy; red[1][wv] = sh; red[2][wv] = sd; red[3][wv] = ma; red[4][wv] = mb; }
    __syncthreads();
    sy = red[0][0] + red[0][1];
    sh = red[1][0] + red[1][1];
    sd = red[2][0] + red[2][1];
    ma = fmaxf(fmaxf(red[3][0], red[3][1]), 1e-20f);
    mb = fmaxf(fmaxf(red[4][0], red[4][1]), 1e-20f);
    const float ny = sqrtf(sy), nh = sqrtf(sh);
    const float ry = 1.f / fmaxf(ny, 1e-12f), rh = 1.f / fmaxf(nh, 1e-12f);
    const float qa = 127.f / ma, qb = 127.f / mb;
    const int ax = (int)rintf(a.x * qa), ay = (int)rintf(a.y * qa),
              az = (int)rintf(a.z * qa), aw = (int)rintf(a.w * qa);
    const int bx_ = (int)rintf(b.x * qb), by_ = (int)rintf(b.y * qb),
              bz = (int)rintf(b.z * qb), bw = (int)rintf(b.w * qb);
    const unsigned int pa = (ax & 0xff) | ((ay & 0xff) << 8) | ((az & 0xff) << 16) | ((aw & 0xff) << 24);
    const unsigned int pb = (bx_ & 0xff) | ((by_ & 0xff) << 8) | ((bz & 0xff) << 16) | ((bw & 0xff) << 24);
    ((unsigned int*)(Qn + (size_t)i * D))[t] = pa;
    ((unsigned int*)(Qn + (size_t)(i + N) * D))[t] = pb;
    if (t == 0) {
        rscale[i]     = ma * ry / 127.f;
        rscale[i + N] = mb * rh / 127.f;
        const float cs = sd / (fmaxf(ny, 1e-8f) * fmaxf(nh, 1e-8f));
        pos[i] = __expf(2.f * cs);
    }
}

// Kernel B (R20's best-measured, 51.0us): 256x256 tile, i8 K=64 MFMA,
// triple-buffer 2-deep counted-vmcnt pipeline, hoisted ds_read offsets.
__global__ __launch_bounds__(512, 2) void simgemm_kernel(const char* __restrict__ Qn,
                                                         const float* __restrict__ rscale,
                                                         float* __restrict__ slab) {
    const int t0 = blockIdx.x;
    const int t = (t0 & 7) * XCHUNK + (t0 >> 3);
    int bx = (int)((sqrtf(8.f * (float)t + 1.f) - 1.f) * 0.5f);
    while ((bx + 1) * (bx + 2) / 2 <= t) ++bx;
    while (bx * (bx + 1) / 2 > t) --bx;
    const int by = t - bx * (bx + 1) / 2;

    __shared__ char As[3 * ABYTES];    // 48 KB
    __shared__ char Bs[3 * ABYTES];    // 48 KB
    __shared__ float redR[256][4];     // 4 KB
    __shared__ float redC[256][2];     // 2 KB  (102 KB)
    const int tid = threadIdx.x;
    const int lane = tid & 63;
    const int w = tid >> 6;
    const int wm = (w >> 2) * 128;
    const int wn = (w & 3) * 64;
    const int fr = lane & 15;
    const int fq = lane >> 4;
    const int rowA0 = by * BM, rowB0 = bx * BM;

    i32x4 acc[8][4] = {};

    // hoisted per-lane ds_read byte offsets (loop-invariant)
    int offA[8], offB[4];
    #pragma unroll
    for (int m = 0; m < 8; ++m) {
        const int row = wm + (m >> 2) * 64 + (m & 3) * 16 + fr;
        offA[m] = row * BKB + ((fq ^ ((row >> 2) & 3)) << 4);
    }
    #pragma unroll
    for (int n = 0; n < 4; ++n) {
        const int row = wn + n * 16 + fr;
        offB[n] = row * BKB + ((fq ^ ((row >> 2) & 3)) << 4);
    }

    const int srow = tid >> 2;
    const int scolb = (((tid & 3) ^ ((tid >> 4) & 3)) << 4);
    const int ldsoffb = w * 1024;

    const char* gA = Qn + (size_t)(rowA0 + srow) * D + scolb;
    const char* gB = Qn + (size_t)(rowB0 + srow) * D + scolb;

    auto SQA = [&](int buf, int k0, int q) {
        gload16b(gA + (size_t)q * 128 * D + k0, As + buf * ABYTES + q * 8192 + ldsoffb);
    };
    auto SQB = [&](int buf, int k0, int q) {
        gload16b(gB + (size_t)q * 128 * D + k0, Bs + buf * ABYTES + q * 8192 + ldsoffb);
    };

    // prologue: stage tiles 0 and 1
    #pragma unroll
    for (int q = 0; q < 2; ++q) { SQA(0, 0, q); SQB(0, 0, q); }
    #pragma unroll
    for (int q = 0; q < 2; ++q) { SQA(1, BKB, q); SQB(1, BKB, q); }
    asm volatile("s_waitcnt vmcnt(4)" ::: "memory");   // tile 0 landed; tile 1 in flight
    __builtin_amdgcn_s_barrier();

    for (int kt = 0; kt < NKT; ++kt) {
        const int cur = kt % 3;
        const char* ab = As + cur * ABYTES;
        const char* bbse = Bs + cur * ABYTES;
        i32x4 fa[8], bb[4];
        #pragma unroll
        for (int m = 0; m < 8; ++m) fa[m] = *(const i32x4*)(ab + offA[m]);
        #pragma unroll
        for (int n = 0; n < 4; ++n) bb[n] = *(const i32x4*)(bbse + offB[n]);
        __builtin_amdgcn_s_barrier();     // prev iter's reads of the stage target done
        if (kt <= NKT - 3) {
            const int nb = (kt + 2) % 3, k2 = (kt + 2) * BKB;
            SQA(nb, k2, 0); SQA(nb, k2, 1);
            SQB(nb, k2, 0); SQB(nb, k2, 1);
        }
        __builtin_amdgcn_s_setprio(1);
        #pragma unroll
        for (int m = 0; m < 4; ++m)
            #pragma unroll
            for (int n = 0; n < 4; ++n)
                acc[m][n] = __builtin_amdgcn_mfma_i32_16x16x64_i8(fa[m], bb[n], acc[m][n], 0, 0, 0);
        #pragma unroll
        for (int m = 0; m < 4; ++m)
            #pragma unroll
            for (int n = 0; n < 4; ++n)
                acc[m + 4][n] = __builtin_amdgcn_mfma_i32_16x16x64_i8(fa[m + 4], bb[n], acc[m + 4][n], 0, 0, 0);
        __builtin_amdgcn_s_setprio(0);
        if (kt <= NKT - 3)      asm volatile("s_waitcnt vmcnt(4)" ::: "memory");
        else if (kt == NKT - 2) asm volatile("s_waitcnt vmcnt(0)" ::: "memory");
    }

    const bool diagblk = (bx == by);
    // dequant + exp + fused row/col partial sums
    float rsb4[4];
    #pragma unroll
    for (int n = 0; n < 4; ++n) rsb4[n] = rscale[rowB0 + wn + n * 16 + fr];
    float colv[4] = {0.f, 0.f, 0.f, 0.f};
    #pragma unroll
    for (int m = 0; m < 8; ++m)
        #pragma unroll
        for (int r = 0; r < 4; ++r) {
            const int grow = wm + m * 16 + fq * 4 + r;
            const float rsa = rscale[rowA0 + grow];
            float rv = 0.f;
            #pragma unroll
            for (int n = 0; n < 4; ++n) {
                const float f = (float)acc[m][n][r] * rsa * rsb4[n];
                float e = __expf(2.f * f);
                const bool diag = diagblk && grow == (wn + n * 16 + fr);
                e = diag ? 0.f : e;
                rv += e;
                colv[n] += e;
            }
            rv += __shfl_xor(rv, 1);
            rv += __shfl_xor(rv, 2);
            rv += __shfl_xor(rv, 4);
            rv += __shfl_xor(rv, 8);
            if (fr == 0) redR[grow][w & 3] = rv;
        }
    if (!diagblk) {
        #pragma unroll
        for (int n = 0; n < 4; ++n) {
            float v = colv[n];
            v += __shfl_xor(v, 16);
            v += __shfl_xor(v, 32);
            if (fq == 0) redC[wn + n * 16 + fr][w >> 2] = v;
        }
    }
    __syncthreads();
    if (tid < 256) {
        const float v = redR[tid][0] + redR[tid][1] + redR[tid][2] + redR[tid][3];
        slab[(size_t)bx * N2ROWS + rowA0 + tid] = v;
    } else if (!diagblk) {
        const int c = tid - 256;
        const float v = redC[c][0] + redC[c][1];
        slab[(size_t)by * N2ROWS + rowB0 + c] = v;
    }
}

// Kernel C (fused): per-row neg, s = pos/neg, block reduce, atomic total;
// the LAST block (device-scope ticket) computes the final loss.
__global__ __launch_bounds__(256) void reduce_kernel(const float* __restrict__ slab,
                                                     const float* __restrict__ pos,
                                                     float* __restrict__ total,
                                                     int* __restrict__ ticket,
                                                     float* __restrict__ out, int N) {
    const int i = blockIdx.x * 256 + threadIdx.x;   // 0..8191
    float neg = 0.f;
    #pragma unroll
    for (int q = 0; q < NT; ++q) neg += slab[(size_t)q * N2ROWS + i];
    const float p = pos[i < N ? i : i - N];
    float s = p / neg;
    #pragma unroll
    for (int o = 32; o > 0; o >>= 1) s += __shfl_xor(s, o);
    __shared__ float red[4];
    if ((threadIdx.x & 63) == 0) red[threadIdx.x >> 6] = s;
    __syncthreads();
    if (threadIdx.x == 0) {
        atomicAdd(total, red[0] + red[1] + red[2] + red[3]);
        __threadfence();
        const int my = atomicAdd(ticket, 1);
        if (my == gridDim.x - 1) {
            const float tot = atomicAdd(total, 0.f);   // device-scope read after all adds
            out[0] = logf(2.f * (float)N) - logf(tot);
        }
    }
}

extern "C" void kernel_launch(void* const* d_in, const int* in_sizes, int n_in,
                              void* d_out, int out_size, void* d_ws, size_t ws_size,
                              hipStream_t stream) {
    const float* y  = (const float*)d_in[0];
    const float* yh = (const float*)d_in[1];
    const int N  = in_sizes[0] / D;   // 4096
    const int N2 = 2 * N;             // 8192

    char* Qn = (char*)d_ws;                                      // [2N][D] i8, 4 MB
    const size_t qn_bytes = (size_t)N2 * D;
    float* slab   = (float*)((char*)d_ws + qn_bytes);            // [32][8192] = 1 MB
    float* pos    = slab + (size_t)NT * N2ROWS;                  // [N]
    float* total  = pos + N;                                     // [1]
    float* rscale = total + 1;                                   // [2N]
    int*   ticket = (int*)(rscale + N2);                         // [1]
    float* out = (float*)d_out;

    prep_kernel<<<N, 128, 0, stream>>>(y, yh, Qn, rscale, pos, total, ticket, N);
    simgemm_kernel<<<NBLK, 512, 0, stream>>>(Qn, rscale, slab);
    reduce_kernel<<<N2 / 256, 256, 0, stream>>>(slab, pos, total, ticket, out, N);
}